// Round 9
// baseline (1142.855 us; speedup 1.0000x reference)
//
#include <hip/hip_runtime.h>
#include <math.h>

#define NN 30000
#define PP 8
#define DM 128
#define EE 1000
#define NNZC 120000
#define DIN (PP*DM)   // 1024

typedef __attribute__((ext_vector_type(8))) short bf16x8;
typedef __attribute__((ext_vector_type(4))) float f32x4;

__device__ __forceinline__ short f2bf(float f) {
    union { float f; unsigned u; } v; v.f = f;
    unsigned r = v.u + 0x7fffu + ((v.u >> 16) & 1u);
    return (short)(r >> 16);
}
__device__ __forceinline__ float bf2f(short s) {
    union { unsigned u; float f; } v;
    v.u = ((unsigned)(unsigned short)s) << 16;
    return v.f;
}

// ---------------------------------------------------------------- CSR build
__global__ void count_kernel(const int* __restrict__ ei, const int* __restrict__ ni,
                             int* __restrict__ ecnt, int* __restrict__ ncnt) {
    int k = blockIdx.x * 256 + threadIdx.x;
    if (k >= NNZC) return;
    atomicAdd(&ecnt[ei[k]], 1);
    atomicAdd(&ncnt[ni[k]], 1);
}

__global__ __launch_bounds__(1024)
void scan_two(const int* __restrict__ ecnt, int* __restrict__ eoff,
              const int* __restrict__ ncnt, int* __restrict__ noff) {
    const int* cnt; int* off; int len;
    if (blockIdx.x == 0) { cnt = ecnt; off = eoff; len = EE; }
    else                 { cnt = ncnt; off = noff; len = NN; }
    __shared__ int wsum[16];
    __shared__ int carrysh;
    int t = threadIdx.x;
    int lane = t & 63, w = t >> 6;
    if (t == 0) carrysh = 0;
    __syncthreads();
    for (int base = 0; base < len; base += 1024) {
        int v = (base + t < len) ? cnt[base + t] : 0;
        int s = v;
        #pragma unroll
        for (int d = 1; d < 64; d <<= 1) {
            int u = __shfl_up(s, d);
            if (lane >= d) s += u;
        }
        if (lane == 63) wsum[w] = s;
        __syncthreads();
        if (t < 16) {
            int ws = wsum[t];
            #pragma unroll
            for (int d = 1; d < 16; d <<= 1) {
                int u = __shfl_up(ws, d);
                if (t >= d) ws += u;
            }
            wsum[t] = ws;
        }
        __syncthreads();
        int c = carrysh;
        int woff = (w > 0) ? wsum[w - 1] : 0;
        if (base + t < len) off[base + t] = c + woff + s - v;
        int total = wsum[15];
        __syncthreads();
        if (t == 0) carrysh = c + total;
    }
    __syncthreads();
    if (t == 0) off[len] = carrysh;
}

__global__ void fill_lists(const int* __restrict__ ei, const int* __restrict__ ni,
                           const int* __restrict__ eoff, const int* __restrict__ noff,
                           int* __restrict__ ecur, int* __restrict__ ncur,
                           int* __restrict__ elist, int* __restrict__ nlist) {
    int k = blockIdx.x * 256 + threadIdx.x;
    if (k >= NNZC) return;
    int e = ei[k];
    int p = atomicAdd(&ecur[e], 1);
    elist[eoff[e] + p] = k;
    int n = ni[k];
    int q = atomicAdd(&ncur[n], 1);
    nlist[noff[n] + q] = k;
}

// ---------------------------------------------------------------- weight transpose+convert
__global__ void transpose_to_bf16(const float* __restrict__ B, short* __restrict__ BT,
                                  int K, int N) {
    __shared__ float tile[32][33];
    int bn = blockIdx.x * 32, bk = blockIdx.y * 32;
    int tx = threadIdx.x & 31, ty = threadIdx.x >> 5;
    #pragma unroll
    for (int yy = ty; yy < 32; yy += 8) {
        int k = bk + yy, n = bn + tx;
        tile[yy][tx] = (k < K && n < N) ? B[(size_t)k * N + n] : 0.f;
    }
    __syncthreads();
    #pragma unroll
    for (int yy = ty; yy < 32; yy += 8) {
        int n = bn + yy, k = bk + tx;
        if (n < N && k < K) BT[(size_t)n * K + k] = f2bf(tile[tx][yy]);
    }
}

// ---------------------------------------------------------------- f32 -> bf16 bulk convert
__global__ void cvt_f2b(const float* __restrict__ in, short* __restrict__ outb, long long total4) {
    long long idx = (long long)blockIdx.x * 256 + threadIdx.x;
    long long stride = (long long)gridDim.x * 256;
    const float4* i4 = (const float4*)in;
    short4* o4 = (short4*)outb;
    for (; idx < total4; idx += stride) {
        float4 v = i4[idx];
        o4[idx] = make_short4(f2bf(v.x), f2bf(v.y), f2bf(v.z), f2bf(v.w));
    }
}

// ---------------------------------------------------------------- bf16 MFMA GEMM
// C[M,Nc] = A[M,K](bf16) @ B^T[Nc,K](bf16)  [+bias][leaky][+bf16 src][BN-stats]
// BM=64, BN=128, 4 waves (2x2 of 32x64), 16x16x32 MFMA, f32 accum, operand-swapped
// (weights as MFMA-A) so each lane's acc quad = 4 consecutive output cols.
// BK==128: single-stage full-K LDS (ONE barrier, all loads in flight together).
// BK==32:  double-buffered pipeline for deep K.
template<int BK, bool HASBIAS, bool LEAKY, bool ADDSRC, bool STATS, bool OUTBF16>
__global__ __launch_bounds__(256)
void gemm_mfma(const short* __restrict__ A, const short* __restrict__ BT,
               const float* __restrict__ bias, const short* __restrict__ srcb,
               void* __restrict__ Cout, float* __restrict__ accum,
               int M, int K, int Nc) {
    constexpr int SMEMB = (BK == 128) ? (64 * 132 + 128 * 132) * 2
                                      : (64 * 36 + 128 * 36) * 2 * 2;
    __shared__ __align__(16) char smem[SMEMB];
    const int tid = threadIdx.x;
    const int lane = tid & 63, wid = tid >> 6;
    const int wm = wid >> 1, wn = wid & 1;
    const int row0 = blockIdx.y * 64, col0 = blockIdx.x * 128;
    f32x4 acc[4][2] = {};

    if constexpr (BK == 128) {
        // ---------------- single-stage: whole K in LDS, one barrier ----------------
        short* As = (short*)smem;            // [64][132]  (pad 4 -> conflict-free)
        short* Bs = As + 64 * 132;           // [128][132]
        const int sr = tid >> 4, sc = tid & 15;
        #pragma unroll
        for (int i = 0; i < 4; ++i) {
            int r = sr + 16 * i, gr = row0 + r;
            bf16x8 v = {0, 0, 0, 0, 0, 0, 0, 0};
            if (gr < M) v = *(const bf16x8*)(A + (size_t)gr * K + sc * 8);
            *(bf16x8*)&As[r * 132 + sc * 8] = v;
        }
        #pragma unroll
        for (int i = 0; i < 8; ++i) {
            int r = sr + 16 * i;
            bf16x8 v = *(const bf16x8*)(BT + (size_t)(col0 + r) * K + sc * 8);
            *(bf16x8*)&Bs[r * 132 + sc * 8] = v;
        }
        __syncthreads();
        #pragma unroll
        for (int ks = 0; ks < 4; ++ks) {
            bf16x8 av[4], bv[2];
            #pragma unroll
            for (int i = 0; i < 4; ++i)
                av[i] = *(const bf16x8*)&Bs[(wn * 64 + i * 16 + (lane & 15)) * 132 + ks * 32 + (lane >> 4) * 8];
            #pragma unroll
            for (int j = 0; j < 2; ++j)
                bv[j] = *(const bf16x8*)&As[(wm * 32 + j * 16 + (lane & 15)) * 132 + ks * 32 + (lane >> 4) * 8];
            #pragma unroll
            for (int i = 0; i < 4; ++i)
                #pragma unroll
                for (int j = 0; j < 2; ++j)
                    acc[i][j] = __builtin_amdgcn_mfma_f32_16x16x32_bf16(av[i], bv[j], acc[i][j], 0, 0, 0);
        }
    } else {
        // ---------------- BK=32 double-buffered pipeline (deep K) ----------------
        short* As0 = (short*)smem;           // [2][64][36]
        short* Bs0 = As0 + 2 * 64 * 36;      // [2][128][36]
        const int ar = tid >> 2, ac = tid & 3;
        bf16x8 ra0, rb0[2], ra1, rb1[2];
        auto loadT = [&](int t, bf16x8& ra, bf16x8* rb) {
            int k0 = t * 32;
            ra = bf16x8{0, 0, 0, 0, 0, 0, 0, 0};
            int gr = row0 + ar;
            if (gr < M) ra = *(const bf16x8*)(A + (size_t)gr * K + k0 + ac * 8);
            #pragma unroll
            for (int c = 0; c < 2; ++c)
                rb[c] = *(const bf16x8*)(BT + (size_t)(col0 + ar + 64 * c) * K + k0 + ac * 8);
        };
        auto writeT = [&](int buf, bf16x8& ra, bf16x8* rb) {
            *(bf16x8*)&As0[buf * 64 * 36 + ar * 36 + ac * 8] = ra;
            #pragma unroll
            for (int c = 0; c < 2; ++c)
                *(bf16x8*)&Bs0[buf * 128 * 36 + (ar + 64 * c) * 36 + ac * 8] = rb[c];
        };
        auto compute = [&](int buf) {
            bf16x8 av[4], bv[2];
            #pragma unroll
            for (int i = 0; i < 4; ++i)
                av[i] = *(const bf16x8*)&Bs0[buf * 128 * 36 + (wn * 64 + i * 16 + (lane & 15)) * 36 + (lane >> 4) * 8];
            #pragma unroll
            for (int j = 0; j < 2; ++j)
                bv[j] = *(const bf16x8*)&As0[buf * 64 * 36 + (wm * 32 + j * 16 + (lane & 15)) * 36 + (lane >> 4) * 8];
            #pragma unroll
            for (int i = 0; i < 4; ++i)
                #pragma unroll
                for (int j = 0; j < 2; ++j)
                    acc[i][j] = __builtin_amdgcn_mfma_f32_16x16x32_bf16(av[i], bv[j], acc[i][j], 0, 0, 0);
        };
        const int NT = K >> 5;
        loadT(0, ra0, rb0);
        for (int t = 0; t < NT; t += 2) {
            __syncthreads();
            loadT(t + 1, ra1, rb1);
            writeT(0, ra0, rb0);
            __syncthreads();
            compute(0);
            __syncthreads();
            if (t + 2 < NT) loadT(t + 2, ra0, rb0);
            writeT(1, ra1, rb1);
            __syncthreads();
            compute(1);
        }
    }

    // ------------- epilogue: direct vectorized stores from registers -------------
    float* Cf = (float*)Cout;
    short* Cb = (short*)Cout;
    f32x4 lsum[4] = {}, lsq[4] = {};

    #pragma unroll
    for (int j = 0; j < 2; ++j) {
        int grow = row0 + wm * 32 + j * 16 + (lane & 15);
        if (grow < M) {
            #pragma unroll
            for (int i = 0; i < 4; ++i) {
                int gcol = col0 + wn * 64 + i * 16 + (lane >> 4) * 4;
                float4 v = make_float4(acc[i][j][0], acc[i][j][1], acc[i][j][2], acc[i][j][3]);
                if (HASBIAS) {
                    float4 bb = *(const float4*)(bias + gcol);
                    v.x += bb.x; v.y += bb.y; v.z += bb.z; v.w += bb.w;
                }
                if (LEAKY) {
                    v.x = v.x > 0.f ? v.x : 0.2f * v.x;
                    v.y = v.y > 0.f ? v.y : 0.2f * v.y;
                    v.z = v.z > 0.f ? v.z : 0.2f * v.z;
                    v.w = v.w > 0.f ? v.w : 0.2f * v.w;
                }
                if (ADDSRC) {
                    short4 sv = *(const short4*)(srcb + (size_t)grow * Nc + gcol);
                    v.x += bf2f(sv.x); v.y += bf2f(sv.y);
                    v.z += bf2f(sv.z); v.w += bf2f(sv.w);
                }
                if (STATS) {
                    lsum[i][0] += v.x; lsq[i][0] += v.x * v.x;
                    lsum[i][1] += v.y; lsq[i][1] += v.y * v.y;
                    lsum[i][2] += v.z; lsq[i][2] += v.z * v.z;
                    lsum[i][3] += v.w; lsq[i][3] += v.w * v.w;
                }
                if (OUTBF16) {
                    *(short4*)(Cb + (size_t)grow * Nc + gcol) =
                        make_short4(f2bf(v.x), f2bf(v.y), f2bf(v.z), f2bf(v.w));
                } else {
                    *(float4*)(Cf + (size_t)grow * Nc + gcol) = v;
                }
            }
        }
    }

    if (STATS) {
        __syncthreads();
        float* fred = (float*)smem;
        fred[tid] = 0.f;
        __syncthreads();
        #pragma unroll
        for (int i = 0; i < 4; ++i) {
            int ch = wn * 64 + i * 16 + (lane >> 4) * 4;   // in-block col == channel
            #pragma unroll
            for (int co = 0; co < 4; ++co) {
                atomicAdd(&fred[ch + co], lsum[i][co]);
                atomicAdd(&fred[128 + ch + co], lsq[i][co]);
            }
        }
        __syncthreads();
        atomicAdd(&accum[tid], fred[tid]);
    }
}

// ---------------------------------------------------------------- BatchNorm stats (float4)
__global__ void bn_stats(const float* __restrict__ a, long long total4, float* __restrict__ accum) {
    int t = threadIdx.x;
    long long idx = (long long)blockIdx.x * 256 + t;
    long long stride = (long long)gridDim.x * 256;
    const float4* a4 = (const float4*)a;
    float s1[4] = {0.f,0.f,0.f,0.f}, s2[4] = {0.f,0.f,0.f,0.f};
    for (; idx < total4; idx += stride) {
        float4 v = a4[idx];
        s1[0] += v.x; s2[0] += v.x * v.x;
        s1[1] += v.y; s2[1] += v.y * v.y;
        s1[2] += v.z; s2[2] += v.z * v.z;
        s1[3] += v.w; s2[3] += v.w * v.w;
    }
    __shared__ float r1[256][4], r2[256][4];
    #pragma unroll
    for (int k = 0; k < 4; ++k) { r1[t][k] = s1[k]; r2[t][k] = s2[k]; }
    __syncthreads();
    if (t < 32) {
        #pragma unroll
        for (int k = 0; k < 4; ++k) {
            float a1 = 0.f, a2 = 0.f;
            #pragma unroll
            for (int u = 0; u < 8; ++u) { a1 += r1[t + u * 32][k]; a2 += r2[t + u * 32][k]; }
            atomicAdd(&accum[t * 4 + k], a1);
            atomicAdd(&accum[128 + t * 4 + k], a2);
        }
    }
}

// ---------------------------------------------------------------- BN finalize+apply (f32; optional bf16 shadow)
template<bool SHADOW>
__global__ void bn_apply_f(float* __restrict__ a, short* __restrict__ shadow, long long total4,
                           const float* __restrict__ accum, const float* __restrict__ g,
                           const float* __restrict__ b, float invM) {
    __shared__ float scs[256];
    int t = threadIdx.x;
    if (t < 128) {
        float mean = accum[t] * invM;
        float var = accum[128 + t] * invM - mean * mean;
        float s = g[t] * rsqrtf(var + 1e-5f);
        scs[t] = s;
        scs[128 + t] = b[t] - mean * s;
    }
    __syncthreads();
    long long idx = (long long)blockIdx.x * 256 + t;
    long long stride = (long long)gridDim.x * 256;
    float4* a4 = (float4*)a;
    short4* s4p = (short4*)shadow;
    for (; idx < total4; idx += stride) {
        int c = (int)((idx & 31) * 4);
        float4 v = a4[idx];
        v.x = v.x * scs[c + 0] + scs[128 + c + 0];
        v.y = v.y * scs[c + 1] + scs[128 + c + 1];
        v.z = v.z * scs[c + 2] + scs[128 + c + 2];
        v.w = v.w * scs[c + 3] + scs[128 + c + 3];
        a4[idx] = v;
        if (SHADOW)
            s4p[idx] = make_short4(f2bf(v.x), f2bf(v.y), f2bf(v.z), f2bf(v.w));
    }
}

// ---------------------------------------------------------------- BN apply bf16 -> f32
__global__ void bn_apply_b2f(const short* __restrict__ inb, float* __restrict__ outp,
                             long long total4, const float* __restrict__ accum,
                             const float* __restrict__ g, const float* __restrict__ b, float invM) {
    __shared__ float scs[256];
    int t = threadIdx.x;
    if (t < 128) {
        float mean = accum[t] * invM;
        float var = accum[128 + t] * invM - mean * mean;
        float s = g[t] * rsqrtf(var + 1e-5f);
        scs[t] = s;
        scs[128 + t] = b[t] - mean * s;
    }
    __syncthreads();
    long long idx = (long long)blockIdx.x * 256 + t;
    long long stride = (long long)gridDim.x * 256;
    const short4* in4 = (const short4*)inb;
    float4* o4 = (float4*)outp;
    for (; idx < total4; idx += stride) {
        int c = (int)((idx & 31) * 4);
        short4 sv = in4[idx];
        float4 v;
        v.x = bf2f(sv.x) * scs[c + 0] + scs[128 + c + 0];
        v.y = bf2f(sv.y) * scs[c + 1] + scs[128 + c + 1];
        v.z = bf2f(sv.z) * scs[c + 2] + scs[128 + c + 2];
        v.w = bf2f(sv.w) * scs[c + 3] + scs[128 + c + 3];
        o4[idx] = v;
    }
}

// ---------------------------------------------------------------- he_attr[e] = sum_{k in edge e} h[node_idx[k]]
__global__ void edge_feat(const int* __restrict__ elist, const int* __restrict__ eoff,
                          const int* __restrict__ nidx, const float* __restrict__ h,
                          float* __restrict__ he, short* __restrict__ heb) {
    int e = blockIdx.x;
    int off = eoff[e], cnt = eoff[e + 1] - off;
    int d = threadIdx.x;  // 128
    float acc = 0.f;
    for (int p = 0; p < cnt; ++p) {
        int k = elist[off + p];
        int n = nidx[k];
        acc += h[(size_t)n * 128 + d];
    }
    he[(size_t)e * 128 + d] = acc;
    heb[(size_t)e * 128 + d] = f2bf(acc);
}

// ---------------------------------------------------------------- attention dots
template<int H>
__global__ void att_dots(const float* __restrict__ feat, const float* __restrict__ att,
                         int attOff, float* __restrict__ out, int M) {
    int wid = threadIdx.x >> 6;
    int lane = threadIdx.x & 63;
    int row = blockIdx.x * 4 + wid;
    if (row >= M) return;
    #pragma unroll
    for (int h = 0; h < H; ++h) {
        const float* fr = feat + (size_t)row * (H * 128) + h * 128;
        const float* ar = att + h * 256 + attOff;
        float v = fr[lane] * ar[lane] + fr[lane + 64] * ar[lane + 64];
        #pragma unroll
        for (int s = 32; s > 0; s >>= 1) v += __shfl_xor(v, s);
        if (lane == 0) out[(size_t)row * H + h] = v;
    }
}

// ---------------------------------------------------------------- per-edge segment softmax
template<int H>
__global__ void edge_softmax(const int* __restrict__ elist, const int* __restrict__ eoff,
                             const int* __restrict__ nidx, const float* __restrict__ ax,
                             const float* __restrict__ ae, float* __restrict__ alpha) {
    constexpr int SLOTS = 256 / H;
    __shared__ float red[256];
    int e = blockIdx.x;
    int off = eoff[e], cnt = eoff[e + 1] - off;
    int t = threadIdx.x;
    int h = t % H, slot = t / H;
    float aeh = ae[(size_t)e * H + h];
    float lmax = -1e30f;
    for (int p = slot; p < cnt; p += SLOTS) {
        int k = elist[off + p];
        int n = nidx[k];
        float v = ax[(size_t)n * H + h] + aeh;
        v = v > 0.f ? v : 0.2f * v;
        alpha[(size_t)k * H + h] = v;
        lmax = fmaxf(lmax, v);
    }
    red[t] = lmax;
    __syncthreads();
    for (int s = SLOTS / 2; s > 0; s >>= 1) {
        if (slot < s) red[slot * H + h] = fmaxf(red[slot * H + h], red[(slot + s) * H + h]);
        __syncthreads();
    }
    float m = red[h];
    __syncthreads();
    float lsum = 0.f;
    for (int p = slot; p < cnt; p += SLOTS) {
        int k = elist[off + p];
        float ex = expf(alpha[(size_t)k * H + h] - m);
        alpha[(size_t)k * H + h] = ex;
        lsum += ex;
    }
    red[t] = lsum;
    __syncthreads();
    for (int s = SLOTS / 2; s > 0; s >>= 1) {
        if (slot < s) red[slot * H + h] += red[(slot + s) * H + h];
        __syncthreads();
    }
    float inv = 1.0f / (red[h] + 1e-16f);
    for (int p = slot; p < cnt; p += SLOTS) {
        int k = elist[off + p];
        alpha[(size_t)k * H + h] *= inv;
    }
}

// ---------------------------------------------------------------- out_e
template<int H>
__global__ void edge_aggregate(const int* __restrict__ elist, const int* __restrict__ eoff,
                               const int* __restrict__ nidx, const float* __restrict__ alpha,
                               const float* __restrict__ xh, float* __restrict__ out_e) {
    int e = blockIdx.x;
    int off = eoff[e], cnt = eoff[e + 1] - off;
    int t = threadIdx.x;            // H*128 threads
    int h = t >> 7;
    float acc = 0.f;
    for (int p = 0; p < cnt; ++p) {
        int k = elist[off + p];
        int n = nidx[k];
        acc += alpha[(size_t)k * H + h] * xh[(size_t)n * (H * 128) + t];
    }
    float binv = cnt > 0 ? 1.0f / (float)cnt : 0.0f;
    out_e[(size_t)e * (H * 128) + t] = acc * binv;
}

// ---------------------------------------------------------------- node side
template<int H>
__global__ void node_aggregate(const int* __restrict__ nlist, const int* __restrict__ noff,
                               const int* __restrict__ eidx, const float* __restrict__ alpha,
                               const float* __restrict__ out_e, const float* __restrict__ bias,
                               float* __restrict__ hout) {
    __shared__ float red[H * 128];
    int n = blockIdx.x;
    int off = noff[n], cnt = noff[n + 1] - off;
    int t = threadIdx.x;            // H*128 threads
    int h = t >> 7;
    float acc = 0.f;
    for (int p = 0; p < cnt; ++p) {
        int k = nlist[off + p];
        int e = eidx[k];
        acc += alpha[(size_t)k * H + h] * out_e[(size_t)e * (H * 128) + t];
    }
    float dinv = cnt > 0 ? 1.0f / (float)cnt : 0.0f;
    acc *= dinv;
    if (H == 1) {
        hout[(size_t)n * 128 + t] += acc + bias[t];
    } else {
        red[t] = acc;
        __syncthreads();
        if (t < 128) {
            float s = 0.f;
            #pragma unroll
            for (int hh = 0; hh < H; ++hh) s += red[hh * 128 + t];
            hout[(size_t)n * 128 + t] += s * (1.0f / H) + bias[t];
        }
    }
}

// ---------------------------------------------------------------- launch
extern "C" void kernel_launch(void* const* d_in, const int* in_sizes, int n_in,
                              void* d_out, int out_size, void* d_ws, size_t ws_size,
                              hipStream_t stream) {
    (void)in_sizes; (void)n_in; (void)out_size; (void)ws_size;
    const float* x        = (const float*)d_in[0];
    const int*   node_idx = (const int*)d_in[1];
    const int*   edge_idx = (const int*)d_in[2];
    const float* W1    = (const float*)d_in[4];
    const float* b1    = (const float*)d_in[5];
    const float* bn1_g = (const float*)d_in[6];
    const float* bn1_b = (const float*)d_in[7];
    const float* h1_lin  = (const float*)d_in[8];
    const float* h1_att  = (const float*)d_in[9];
    const float* h1_bias = (const float*)d_in[10];
    const float* bn2_g = (const float*)d_in[11];
    const float* bn2_b = (const float*)d_in[12];
    const float* h2_lin  = (const float*)d_in[13];
    const float* h2_att  = (const float*)d_in[14];
    const float* h2_bias = (const float*)d_in[15];
    const float* bn3_g = (const float*)d_in[16];
    const float* bn3_b = (const float*)d_in[17];
    const float* W2    = (const float*)d_in[18];
    const float* b2    = (const float*)d_in[19];
    const float* bn4_g = (const float*)d_in[20];
    const float* bn4_b = (const float*)d_in[21];
    float* out = (float*)d_out;

    char* ws = (char*)d_ws;
    size_t off = 0;
    auto alloc = [&](size_t bytes) -> void* {
        void* p = ws + off;
        off = (off + bytes + 255) & ~(size_t)255;
        return p;
    };
    float* h     = (float*)alloc((size_t)NN * 128 * 4);
    float* xh    = (float*)alloc((size_t)NN * 512 * 4);
    float* he    = (float*)alloc((size_t)EE * 128 * 4);
    float* eh    = (float*)alloc((size_t)EE * 512 * 4);
    float* oute  = (float*)alloc((size_t)EE * 512 * 4);
    float* ax    = (float*)alloc((size_t)NN * 4 * 4);
    float* ae    = (float*)alloc((size_t)EE * 4 * 4);
    float* alpha = (float*)alloc((size_t)NNZC * 4 * 4);
    float* accum = (float*)alloc(256 * 4);
    short* hb    = (short*)alloc((size_t)NN * 128 * 2);    // bf16 shadow of h
    short* heb   = (short*)alloc((size_t)EE * 128 * 2);    // bf16 shadow of he
    short* W1T   = (short*)alloc((size_t)128 * DIN * 2);
    short* h1T   = (short*)alloc((size_t)512 * 128 * 2);
    short* h2T   = (short*)alloc((size_t)128 * 128 * 2);
    short* W2T   = (short*)alloc((size_t)DIN * 128 * 2);
    int* ecnt  = (int*)alloc(EE * 4);
    int* eoff  = (int*)alloc((EE + 1) * 4);
    int* ecur  = (int*)alloc(EE * 4);
    int* elist = (int*)alloc(NNZC * 4);
    int* ncnt  = (int*)alloc(NN * 4);
    int* noff  = (int*)alloc((NN + 1) * 4);
    int* ncur  = (int*)alloc(NN * 4);
    int* nlist = (int*)alloc(NNZC * 4);

    short* xb   = (short*)d_out;   // bf16 copy of x in dead first half of d_out
    short* outb = (short*)xh;      // pre-BN4 bf16 scratch (xh dead by then)

    hipMemsetAsync(ecnt, 0, EE * 4, stream);
    hipMemsetAsync(ncnt, 0, NN * 4, stream);
    hipMemsetAsync(ecur, 0, EE * 4, stream);
    hipMemsetAsync(ncur, 0, NN * 4, stream);

    count_kernel<<<(NNZC + 255) / 256, 256, 0, stream>>>(edge_idx, node_idx, ecnt, ncnt);
    cvt_f2b<<<2048, 256, 0, stream>>>(x, xb, (long long)NN * DIN / 4);
    transpose_to_bf16<<<dim3(4, 32), 256, 0, stream>>>(W1, W1T, DIN, 128);
    transpose_to_bf16<<<dim3(16, 4), 256, 0, stream>>>(h1_lin, h1T, 128, 512);
    transpose_to_bf16<<<dim3(4, 4), 256, 0, stream>>>(h2_lin, h2T, 128, 128);
    transpose_to_bf16<<<dim3(32, 4), 256, 0, stream>>>(W2, W2T, 128, DIN);
    scan_two<<<2, 1024, 0, stream>>>(ecnt, eoff, ncnt, noff);
    fill_lists<<<(NNZC + 255) / 256, 256, 0, stream>>>(edge_idx, node_idx, eoff, noff,
                                                       ecur, ncur, elist, nlist);

    const int MB64 = (NN + 63) / 64;    // 469
    const int EB64 = (EE + 63) / 64;    // 16

    // h = leaky(xb @ W1 + b1)   [MFMA, K=1024 pipeline, BN1 stats fused]
    hipMemsetAsync(accum, 0, 256 * 4, stream);
    gemm_mfma<32, true, true, false, true, false><<<dim3(1, MB64), 256, 0, stream>>>(
        xb, W1T, b1, nullptr, h, accum, NN, DIN, 128);
    bn_apply_f<true><<<1024, 256, 0, stream>>>(h, hb, (long long)NN * 128 / 4, accum,
                                               bn1_g, bn1_b, 1.0f / NN);

    // ---- hconv1 (heads=4) ----
    edge_feat<<<EE, 128, 0, stream>>>(elist, eoff, node_idx, h, he, heb);
    gemm_mfma<128, false, false, false, false, false><<<dim3(4, MB64), 256, 0, stream>>>(
        hb, h1T, nullptr, nullptr, xh, nullptr, NN, 128, 512);
    gemm_mfma<128, false, false, false, false, false><<<dim3(4, EB64), 256, 0, stream>>>(
        heb, h1T, nullptr, nullptr, eh, nullptr, EE, 128, 512);
    att_dots<4><<<(NN + 3) / 4, 256, 0, stream>>>(xh, h1_att, 0, ax, NN);
    att_dots<4><<<(EE + 3) / 4, 256, 0, stream>>>(eh, h1_att, 128, ae, EE);
    edge_softmax<4><<<EE, 256, 0, stream>>>(elist, eoff, node_idx, ax, ae, alpha);
    edge_aggregate<4><<<EE, 512, 0, stream>>>(elist, eoff, node_idx, alpha, xh, oute);
    node_aggregate<4><<<NN, 512, 0, stream>>>(nlist, noff, edge_idx, alpha, oute, h1_bias, h);

    // BN2
    hipMemsetAsync(accum, 0, 256 * 4, stream);
    bn_stats<<<512, 256, 0, stream>>>(h, (long long)NN * 128 / 4, accum);
    bn_apply_f<true><<<1024, 256, 0, stream>>>(h, hb, (long long)NN * 128 / 4, accum,
                                               bn2_g, bn2_b, 1.0f / NN);

    // ---- hconv2 (heads=1) ----
    edge_feat<<<EE, 128, 0, stream>>>(elist, eoff, node_idx, h, he, heb);
    gemm_mfma<128, false, false, false, false, false><<<dim3(1, MB64), 256, 0, stream>>>(
        hb, h2T, nullptr, nullptr, xh, nullptr, NN, 128, 128);
    gemm_mfma<128, false, false, false, false, false><<<dim3(1, EB64), 256, 0, stream>>>(
        heb, h2T, nullptr, nullptr, eh, nullptr, EE, 128, 128);
    att_dots<1><<<(NN + 3) / 4, 256, 0, stream>>>(xh, h2_att, 0, ax, NN);
    att_dots<1><<<(EE + 3) / 4, 256, 0, stream>>>(eh, h2_att, 128, ae, EE);
    edge_softmax<1><<<EE, 256, 0, stream>>>(elist, eoff, node_idx, ax, ae, alpha);
    edge_aggregate<1><<<EE, 128, 0, stream>>>(elist, eoff, node_idx, alpha, xh, oute);
    node_aggregate<1><<<NN, 128, 0, stream>>>(nlist, noff, edge_idx, alpha, oute, h2_bias, h);

    // BN3 (shadow feeds W2)
    hipMemsetAsync(accum, 0, 256 * 4, stream);
    bn_stats<<<512, 256, 0, stream>>>(h, (long long)NN * 128 / 4, accum);
    bn_apply_f<true><<<1024, 256, 0, stream>>>(h, hb, (long long)NN * 128 / 4, accum,
                                               bn3_g, bn3_b, 1.0f / NN);

    // out_pre = xb + leaky(hb @ W2 + b2) -> bf16 scratch [MFMA + BN4 stats fused]
    hipMemsetAsync(accum, 0, 256 * 4, stream);
    gemm_mfma<128, true, true, true, true, true><<<dim3(8, MB64), 256, 0, stream>>>(
        hb, W2T, b2, xb, outb, accum, NN, 128, DIN);

    // BN4: bf16 -> f32 out (overwrites all of d_out incl. the xb scratch region)
    bn_apply_b2f<<<2048, 256, 0, stream>>>(outb, out, (long long)NN * DIN / 4, accum,
                                           bn4_g, bn4_b, 1.0f / (NN * PP));
}

// Round 10
// 858.109 us; speedup vs baseline: 1.3318x; 1.3318x over previous
//
#include <hip/hip_runtime.h>
#include <math.h>

#define NN 30000
#define PP 8
#define DM 128
#define EE 1000
#define NNZC 120000
#define DIN (PP*DM)   // 1024

typedef __attribute__((ext_vector_type(8))) short bf16x8;
typedef __attribute__((ext_vector_type(4))) float f32x4;

__device__ __forceinline__ short f2bf(float f) {
    union { float f; unsigned u; } v; v.f = f;
    unsigned r = v.u + 0x7fffu + ((v.u >> 16) & 1u);
    return (short)(r >> 16);
}
__device__ __forceinline__ float bf2f(short s) {
    union { unsigned u; float f; } v;
    v.u = ((unsigned)(unsigned short)s) << 16;
    return v.f;
}

// ---------------------------------------------------------------- CSR build
__global__ void count_kernel(const int* __restrict__ ei, const int* __restrict__ ni,
                             int* __restrict__ ecnt, int* __restrict__ ncnt) {
    int k = blockIdx.x * 256 + threadIdx.x;
    if (k >= NNZC) return;
    atomicAdd(&ecnt[ei[k]], 1);
    atomicAdd(&ncnt[ni[k]], 1);
}

__global__ __launch_bounds__(1024)
void scan_two(const int* __restrict__ ecnt, int* __restrict__ eoff,
              const int* __restrict__ ncnt, int* __restrict__ noff) {
    const int* cnt; int* off; int len;
    if (blockIdx.x == 0) { cnt = ecnt; off = eoff; len = EE; }
    else                 { cnt = ncnt; off = noff; len = NN; }
    __shared__ int wsum[16];
    __shared__ int carrysh;
    int t = threadIdx.x;
    int lane = t & 63, w = t >> 6;
    if (t == 0) carrysh = 0;
    __syncthreads();
    for (int base = 0; base < len; base += 1024) {
        int v = (base + t < len) ? cnt[base + t] : 0;
        int s = v;
        #pragma unroll
        for (int d = 1; d < 64; d <<= 1) {
            int u = __shfl_up(s, d);
            if (lane >= d) s += u;
        }
        if (lane == 63) wsum[w] = s;
        __syncthreads();
        if (t < 16) {
            int ws = wsum[t];
            #pragma unroll
            for (int d = 1; d < 16; d <<= 1) {
                int u = __shfl_up(ws, d);
                if (t >= d) ws += u;
            }
            wsum[t] = ws;
        }
        __syncthreads();
        int c = carrysh;
        int woff = (w > 0) ? wsum[w - 1] : 0;
        if (base + t < len) off[base + t] = c + woff + s - v;
        int total = wsum[15];
        __syncthreads();
        if (t == 0) carrysh = c + total;
    }
    __syncthreads();
    if (t == 0) off[len] = carrysh;
}

__global__ void fill_lists(const int* __restrict__ ei, const int* __restrict__ ni,
                           const int* __restrict__ eoff, const int* __restrict__ noff,
                           int* __restrict__ ecur, int* __restrict__ ncur,
                           int* __restrict__ elist, int* __restrict__ nlist) {
    int k = blockIdx.x * 256 + threadIdx.x;
    if (k >= NNZC) return;
    int e = ei[k];
    int p = atomicAdd(&ecur[e], 1);
    elist[eoff[e] + p] = k;
    int n = ni[k];
    int q = atomicAdd(&ncur[n], 1);
    nlist[noff[n] + q] = k;
}

// ---------------------------------------------------------------- weight transpose+convert
__global__ void transpose_to_bf16(const float* __restrict__ B, short* __restrict__ BT,
                                  int K, int N) {
    __shared__ float tile[32][33];
    int bn = blockIdx.x * 32, bk = blockIdx.y * 32;
    int tx = threadIdx.x & 31, ty = threadIdx.x >> 5;
    #pragma unroll
    for (int yy = ty; yy < 32; yy += 8) {
        int k = bk + yy, n = bn + tx;
        tile[yy][tx] = (k < K && n < N) ? B[(size_t)k * N + n] : 0.f;
    }
    __syncthreads();
    #pragma unroll
    for (int yy = ty; yy < 32; yy += 8) {
        int n = bn + yy, k = bk + tx;
        if (n < N && k < K) BT[(size_t)n * K + k] = f2bf(tile[tx][yy]);
    }
}

// ---------------------------------------------------------------- bf16 MFMA GEMM  (R3 structure — measured best)
// C[M,Nc] = A[M,K](f32, cvt on stage) @ B^T[Nc,K](bf16)  [+bias][leaky][+src][BN-stats]
// BM=BN=128, BK=32, 4 waves (2x2 of 64x64), 16x16x32 MFMA, f32 accum.
// Epilogue: wave-coalesced register stores (lane&15 -> consecutive cols).
template<bool HASBIAS, bool LEAKY, bool ADDSRC, bool STATS, bool OUTBF16>
__global__ __launch_bounds__(256)
void gemm_mfma(const float* __restrict__ A, const short* __restrict__ BT,
               const float* __restrict__ bias, const float* __restrict__ src,
               void* __restrict__ Cout, float* __restrict__ accum, int M, int K, int Nc) {
    __shared__ short As[128 * 40];   // row stride 40 shorts (80B): bank-uniform
    __shared__ short Bs[128 * 40];
    const int tid = threadIdx.x;
    const int lane = tid & 63, wid = tid >> 6;
    const int wm = wid >> 1, wn = wid & 1;
    const int row0 = blockIdx.y * 128, col0 = blockIdx.x * 128;
    const int srow = tid >> 2, skq = tid & 3;

    f32x4 acc[4][4] = {};
    const int NT = K >> 5;

    struct Stage { float4 fa[2][2]; bf16x8 b[2]; };
    Stage s0, s1;

    auto loadT = [&](int t, Stage& s) {
        int k0 = t << 5;
        #pragma unroll
        for (int c = 0; c < 2; ++c) {
            int gr = row0 + srow + 64 * c;
            float4 z = make_float4(0.f, 0.f, 0.f, 0.f);
            s.fa[c][0] = z; s.fa[c][1] = z;
            if (gr < M) {
                const float4* p = (const float4*)(A + (size_t)gr * K + k0 + skq * 8);
                s.fa[c][0] = p[0]; s.fa[c][1] = p[1];
            }
            int gc = col0 + srow + 64 * c;
            s.b[c] = *(const bf16x8*)(BT + (size_t)gc * K + k0 + skq * 8);
        }
    };
    auto writeT = [&](Stage& s) {
        #pragma unroll
        for (int c = 0; c < 2; ++c) {
            bf16x8 t8;
            t8[0] = f2bf(s.fa[c][0].x); t8[1] = f2bf(s.fa[c][0].y);
            t8[2] = f2bf(s.fa[c][0].z); t8[3] = f2bf(s.fa[c][0].w);
            t8[4] = f2bf(s.fa[c][1].x); t8[5] = f2bf(s.fa[c][1].y);
            t8[6] = f2bf(s.fa[c][1].z); t8[7] = f2bf(s.fa[c][1].w);
            *(bf16x8*)&As[(srow + 64 * c) * 40 + skq * 8] = t8;
            *(bf16x8*)&Bs[(srow + 64 * c) * 40 + skq * 8] = s.b[c];
        }
    };
    auto compute = [&]() {
        bf16x8 av[4], bv[4];
        #pragma unroll
        for (int i = 0; i < 4; ++i)
            av[i] = *(const bf16x8*)&As[(wm * 64 + i * 16 + (lane & 15)) * 40 + (lane >> 4) * 8];
        #pragma unroll
        for (int j = 0; j < 4; ++j)
            bv[j] = *(const bf16x8*)&Bs[(wn * 64 + j * 16 + (lane & 15)) * 40 + (lane >> 4) * 8];
        #pragma unroll
        for (int i = 0; i < 4; ++i)
            #pragma unroll
            for (int j = 0; j < 4; ++j)
                acc[i][j] = __builtin_amdgcn_mfma_f32_16x16x32_bf16(av[i], bv[j], acc[i][j], 0, 0, 0);
    };

    loadT(0, s0);
    for (int t = 0; t < NT; t += 2) {
        __syncthreads();
        loadT(t + 1, s1);
        writeT(s0);
        __syncthreads();
        compute();
        __syncthreads();
        if (t + 2 < NT) loadT(t + 2, s0);
        writeT(s1);
        __syncthreads();
        compute();
    }

    // epilogue: C/D layout col=lane&15 (consecutive across lanes -> wave-coalesced),
    // row=(lane>>4)*4+q
    float* Cf = (float*)Cout;
    short* Cb = (short*)Cout;
    float lsum[4] = {0.f, 0.f, 0.f, 0.f}, lsq[4] = {0.f, 0.f, 0.f, 0.f};
    #pragma unroll
    for (int i = 0; i < 4; ++i) {
        #pragma unroll
        for (int q = 0; q < 4; ++q) {
            int row = row0 + wm * 64 + i * 16 + (lane >> 4) * 4 + q;
            if (row < M) {
                #pragma unroll
                for (int j = 0; j < 4; ++j) {
                    int col = col0 + wn * 64 + j * 16 + (lane & 15);
                    float val = acc[i][j][q];
                    if (HASBIAS) val += bias[col];
                    if (LEAKY)   val = val > 0.f ? val : 0.2f * val;
                    if (ADDSRC)  val += src[(size_t)row * Nc + col];
                    if (STATS) { lsum[j] += val; lsq[j] += val * val; }
                    if (OUTBF16) Cb[(size_t)row * Nc + col] = f2bf(val);
                    else         Cf[(size_t)row * Nc + col] = val;
                }
            }
        }
    }
    if (STATS) {
        __syncthreads();                  // done with As
        float* sred = (float*)As;         // 256 floats scratch
        sred[tid] = 0.f;
        __syncthreads();
        int ch = wn * 64 + (lane & 15);   // channel = in-block col (col0 % 128 == 0)
        #pragma unroll
        for (int j = 0; j < 4; ++j) {
            atomicAdd(&sred[ch + j * 16], lsum[j]);
            atomicAdd(&sred[128 + ch + j * 16], lsq[j]);
        }
        __syncthreads();
        atomicAdd(&accum[tid], sred[tid]);
    }
}

// ---------------------------------------------------------------- BatchNorm stats (float4)
__global__ void bn_stats(const float* __restrict__ a, long long total4, float* __restrict__ accum) {
    int t = threadIdx.x;
    long long idx = (long long)blockIdx.x * 256 + t;
    long long stride = (long long)gridDim.x * 256;
    const float4* a4 = (const float4*)a;
    float s1[4] = {0.f,0.f,0.f,0.f}, s2[4] = {0.f,0.f,0.f,0.f};
    for (; idx < total4; idx += stride) {
        float4 v = a4[idx];
        s1[0] += v.x; s2[0] += v.x * v.x;
        s1[1] += v.y; s2[1] += v.y * v.y;
        s1[2] += v.z; s2[2] += v.z * v.z;
        s1[3] += v.w; s2[3] += v.w * v.w;
    }
    __shared__ float r1[256][4], r2[256][4];
    #pragma unroll
    for (int k = 0; k < 4; ++k) { r1[t][k] = s1[k]; r2[t][k] = s2[k]; }
    __syncthreads();
    if (t < 32) {
        #pragma unroll
        for (int k = 0; k < 4; ++k) {
            float a1 = 0.f, a2 = 0.f;
            #pragma unroll
            for (int u = 0; u < 8; ++u) { a1 += r1[t + u * 32][k]; a2 += r2[t + u * 32][k]; }
            atomicAdd(&accum[t * 4 + k], a1);
            atomicAdd(&accum[128 + t * 4 + k], a2);
        }
    }
}

// ---------------------------------------------------------------- BN finalize+apply (f32 in/out)
__global__ void bn_apply_f(float* __restrict__ a, long long total4,
                           const float* __restrict__ accum, const float* __restrict__ g,
                           const float* __restrict__ b, float invM) {
    __shared__ float scs[256];
    int t = threadIdx.x;
    if (t < 128) {
        float mean = accum[t] * invM;
        float var = accum[128 + t] * invM - mean * mean;
        float s = g[t] * rsqrtf(var + 1e-5f);
        scs[t] = s;
        scs[128 + t] = b[t] - mean * s;
    }
    __syncthreads();
    long long idx = (long long)blockIdx.x * 256 + t;
    long long stride = (long long)gridDim.x * 256;
    float4* a4 = (float4*)a;
    for (; idx < total4; idx += stride) {
        int c = (int)((idx & 31) * 4);
        float4 v = a4[idx];
        v.x = v.x * scs[c + 0] + scs[128 + c + 0];
        v.y = v.y * scs[c + 1] + scs[128 + c + 1];
        v.z = v.z * scs[c + 2] + scs[128 + c + 2];
        v.w = v.w * scs[c + 3] + scs[128 + c + 3];
        a4[idx] = v;
    }
}

// ---------------------------------------------------------------- BN apply bf16 -> f32
__global__ void bn_apply_b2f(const short* __restrict__ inb, float* __restrict__ outp,
                             long long total4, const float* __restrict__ accum,
                             const float* __restrict__ g, const float* __restrict__ b, float invM) {
    __shared__ float scs[256];
    int t = threadIdx.x;
    if (t < 128) {
        float mean = accum[t] * invM;
        float var = accum[128 + t] * invM - mean * mean;
        float s = g[t] * rsqrtf(var + 1e-5f);
        scs[t] = s;
        scs[128 + t] = b[t] - mean * s;
    }
    __syncthreads();
    long long idx = (long long)blockIdx.x * 256 + t;
    long long stride = (long long)gridDim.x * 256;
    const short4* in4 = (const short4*)inb;
    float4* o4 = (float4*)outp;
    for (; idx < total4; idx += stride) {
        int c = (int)((idx & 31) * 4);
        short4 sv = in4[idx];
        float4 v;
        v.x = bf2f(sv.x) * scs[c + 0] + scs[128 + c + 0];
        v.y = bf2f(sv.y) * scs[c + 1] + scs[128 + c + 1];
        v.z = bf2f(sv.z) * scs[c + 2] + scs[128 + c + 2];
        v.w = bf2f(sv.w) * scs[c + 3] + scs[128 + c + 3];
        o4[idx] = v;
    }
}

// ---------------------------------------------------------------- he_attr[e] = sum_{k in edge e} h[node_idx[k]]
__global__ void edge_feat(const int* __restrict__ elist, const int* __restrict__ eoff,
                          const int* __restrict__ nidx, const float* __restrict__ h,
                          float* __restrict__ he) {
    int e = blockIdx.x;
    int off = eoff[e], cnt = eoff[e + 1] - off;
    int d = threadIdx.x;  // 128
    float acc = 0.f;
    for (int p = 0; p < cnt; ++p) {
        int k = elist[off + p];
        int n = nidx[k];
        acc += h[(size_t)n * 128 + d];
    }
    he[(size_t)e * 128 + d] = acc;
}

// ---------------------------------------------------------------- attention dots
template<int H>
__global__ void att_dots(const float* __restrict__ feat, const float* __restrict__ att,
                         int attOff, float* __restrict__ out, int M) {
    int wid = threadIdx.x >> 6;
    int lane = threadIdx.x & 63;
    int row = blockIdx.x * 4 + wid;
    if (row >= M) return;
    #pragma unroll
    for (int h = 0; h < H; ++h) {
        const float* fr = feat + (size_t)row * (H * 128) + h * 128;
        const float* ar = att + h * 256 + attOff;
        float v = fr[lane] * ar[lane] + fr[lane + 64] * ar[lane + 64];
        #pragma unroll
        for (int s = 32; s > 0; s >>= 1) v += __shfl_xor(v, s);
        if (lane == 0) out[(size_t)row * H + h] = v;
    }
}

// ---------------------------------------------------------------- per-edge segment softmax
template<int H>
__global__ void edge_softmax(const int* __restrict__ elist, const int* __restrict__ eoff,
                             const int* __restrict__ nidx, const float* __restrict__ ax,
                             const float* __restrict__ ae, float* __restrict__ alpha) {
    constexpr int SLOTS = 256 / H;
    __shared__ float red[256];
    int e = blockIdx.x;
    int off = eoff[e], cnt = eoff[e + 1] - off;
    int t = threadIdx.x;
    int h = t % H, slot = t / H;
    float aeh = ae[(size_t)e * H + h];
    float lmax = -1e30f;
    for (int p = slot; p < cnt; p += SLOTS) {
        int k = elist[off + p];
        int n = nidx[k];
        float v = ax[(size_t)n * H + h] + aeh;
        v = v > 0.f ? v : 0.2f * v;
        alpha[(size_t)k * H + h] = v;
        lmax = fmaxf(lmax, v);
    }
    red[t] = lmax;
    __syncthreads();
    for (int s = SLOTS / 2; s > 0; s >>= 1) {
        if (slot < s) red[slot * H + h] = fmaxf(red[slot * H + h], red[(slot + s) * H + h]);
        __syncthreads();
    }
    float m = red[h];
    __syncthreads();
    float lsum = 0.f;
    for (int p = slot; p < cnt; p += SLOTS) {
        int k = elist[off + p];
        float ex = expf(alpha[(size_t)k * H + h] - m);
        alpha[(size_t)k * H + h] = ex;
        lsum += ex;
    }
    red[t] = lsum;
    __syncthreads();
    for (int s = SLOTS / 2; s > 0; s >>= 1) {
        if (slot < s) red[slot * H + h] += red[(slot + s) * H + h];
        __syncthreads();
    }
    float inv = 1.0f / (red[h] + 1e-16f);
    for (int p = slot; p < cnt; p += SLOTS) {
        int k = elist[off + p];
        alpha[(size_t)k * H + h] *= inv;
    }
}

// ---------------------------------------------------------------- out_e
template<int H>
__global__ void edge_aggregate(const int* __restrict__ elist, const int* __restrict__ eoff,
                               const int* __restrict__ nidx, const float* __restrict__ alpha,
                               const float* __restrict__ xh, float* __restrict__ out_e) {
    int e = blockIdx.x;
    int off = eoff[e], cnt = eoff[e + 1] - off;
    int t = threadIdx.x;            // H*128 threads
    int h = t >> 7;
    float acc = 0.f;
    for (int p = 0; p < cnt; ++p) {
        int k = elist[off + p];
        int n = nidx[k];
        acc += alpha[(size_t)k * H + h] * xh[(size_t)n * (H * 128) + t];
    }
    float binv = cnt > 0 ? 1.0f / (float)cnt : 0.0f;
    out_e[(size_t)e * (H * 128) + t] = acc * binv;
}

// ---------------------------------------------------------------- node side
template<int H>
__global__ void node_aggregate(const int* __restrict__ nlist, const int* __restrict__ noff,
                               const int* __restrict__ eidx, const float* __restrict__ alpha,
                               const float* __restrict__ out_e, const float* __restrict__ bias,
                               float* __restrict__ hout) {
    __shared__ float red[H * 128];
    int n = blockIdx.x;
    int off = noff[n], cnt = noff[n + 1] - off;
    int t = threadIdx.x;            // H*128 threads
    int h = t >> 7;
    float acc = 0.f;
    for (int p = 0; p < cnt; ++p) {
        int k = nlist[off + p];
        int e = eidx[k];
        acc += alpha[(size_t)k * H + h] * out_e[(size_t)e * (H * 128) + t];
    }
    float dinv = cnt > 0 ? 1.0f / (float)cnt : 0.0f;
    acc *= dinv;
    if (H == 1) {
        hout[(size_t)n * 128 + t] += acc + bias[t];
    } else {
        red[t] = acc;
        __syncthreads();
        if (t < 128) {
            float s = 0.f;
            #pragma unroll
            for (int hh = 0; hh < H; ++hh) s += red[hh * 128 + t];
            hout[(size_t)n * 128 + t] += s * (1.0f / H) + bias[t];
        }
    }
}

// ---------------------------------------------------------------- launch
extern "C" void kernel_launch(void* const* d_in, const int* in_sizes, int n_in,
                              void* d_out, int out_size, void* d_ws, size_t ws_size,
                              hipStream_t stream) {
    (void)in_sizes; (void)n_in; (void)out_size; (void)ws_size;
    const float* x        = (const float*)d_in[0];
    const int*   node_idx = (const int*)d_in[1];
    const int*   edge_idx = (const int*)d_in[2];
    const float* W1    = (const float*)d_in[4];
    const float* b1    = (const float*)d_in[5];
    const float* bn1_g = (const float*)d_in[6];
    const float* bn1_b = (const float*)d_in[7];
    const float* h1_lin  = (const float*)d_in[8];
    const float* h1_att  = (const float*)d_in[9];
    const float* h1_bias = (const float*)d_in[10];
    const float* bn2_g = (const float*)d_in[11];
    const float* bn2_b = (const float*)d_in[12];
    const float* h2_lin  = (const float*)d_in[13];
    const float* h2_att  = (const float*)d_in[14];
    const float* h2_bias = (const float*)d_in[15];
    const float* bn3_g = (const float*)d_in[16];
    const float* bn3_b = (const float*)d_in[17];
    const float* W2    = (const float*)d_in[18];
    const float* b2    = (const float*)d_in[19];
    const float* bn4_g = (const float*)d_in[20];
    const float* bn4_b = (const float*)d_in[21];
    float* out = (float*)d_out;

    char* ws = (char*)d_ws;
    size_t off = 0;
    auto alloc = [&](size_t bytes) -> void* {
        void* p = ws + off;
        off = (off + bytes + 255) & ~(size_t)255;
        return p;
    };
    float* h     = (float*)alloc((size_t)NN * 128 * 4);
    float* xh    = (float*)alloc((size_t)NN * 512 * 4);
    float* he    = (float*)alloc((size_t)EE * 128 * 4);
    float* eh    = (float*)alloc((size_t)EE * 512 * 4);
    float* oute  = (float*)alloc((size_t)EE * 512 * 4);
    float* ax    = (float*)alloc((size_t)NN * 4 * 4);
    float* ae    = (float*)alloc((size_t)EE * 4 * 4);
    float* alpha = (float*)alloc((size_t)NNZC * 4 * 4);
    float* accum = (float*)alloc(256 * 4);
    short* W1T   = (short*)alloc((size_t)128 * DIN * 2);
    short* h1T   = (short*)alloc((size_t)512 * 128 * 2);
    short* h2T   = (short*)alloc((size_t)128 * 128 * 2);
    short* W2T   = (short*)alloc((size_t)DIN * 128 * 2);
    int* ecnt  = (int*)alloc(EE * 4);
    int* eoff  = (int*)alloc((EE + 1) * 4);
    int* ecur  = (int*)alloc(EE * 4);
    int* elist = (int*)alloc(NNZC * 4);
    int* ncnt  = (int*)alloc(NN * 4);
    int* noff  = (int*)alloc((NN + 1) * 4);
    int* ncur  = (int*)alloc(NN * 4);
    int* nlist = (int*)alloc(NNZC * 4);

    short* outb = (short*)xh;   // pre-BN4 bf16 scratch (xh dead by then)

    hipMemsetAsync(ecnt, 0, EE * 4, stream);
    hipMemsetAsync(ncnt, 0, NN * 4, stream);
    hipMemsetAsync(ecur, 0, EE * 4, stream);
    hipMemsetAsync(ncur, 0, NN * 4, stream);

    count_kernel<<<(NNZC + 255) / 256, 256, 0, stream>>>(edge_idx, node_idx, ecnt, ncnt);
    transpose_to_bf16<<<dim3(4, 32), 256, 0, stream>>>(W1, W1T, DIN, 128);
    transpose_to_bf16<<<dim3(16, 4), 256, 0, stream>>>(h1_lin, h1T, 128, 512);
    transpose_to_bf16<<<dim3(4, 4), 256, 0, stream>>>(h2_lin, h2T, 128, 128);
    transpose_to_bf16<<<dim3(32, 4), 256, 0, stream>>>(W2, W2T, 128, DIN);
    scan_two<<<2, 1024, 0, stream>>>(ecnt, eoff, ncnt, noff);
    fill_lists<<<(NNZC + 255) / 256, 256, 0, stream>>>(edge_idx, node_idx, eoff, noff,
                                                       ecur, ncur, elist, nlist);

    const int MB = (NN + 127) / 128;   // 235

    // h = leaky(x @ W1 + b1)   [MFMA + BN1 stats fused]
    hipMemsetAsync(accum, 0, 256 * 4, stream);
    gemm_mfma<true, true, false, true, false><<<dim3(1, MB), 256, 0, stream>>>(
        x, W1T, b1, nullptr, h, accum, NN, DIN, 128);
    bn_apply_f<<<1024, 256, 0, stream>>>(h, (long long)NN * 128 / 4, accum, bn1_g, bn1_b, 1.0f / NN);

    // ---- hconv1 (heads=4) ----
    edge_feat<<<EE, 128, 0, stream>>>(elist, eoff, node_idx, h, he);
    gemm_mfma<false, false, false, false, false><<<dim3(4, MB), 256, 0, stream>>>(
        h, h1T, nullptr, nullptr, xh, nullptr, NN, 128, 512);
    gemm_mfma<false, false, false, false, false><<<dim3(4, 8), 256, 0, stream>>>(
        he, h1T, nullptr, nullptr, eh, nullptr, EE, 128, 512);
    att_dots<4><<<(NN + 3) / 4, 256, 0, stream>>>(xh, h1_att, 0, ax, NN);
    att_dots<4><<<(EE + 3) / 4, 256, 0, stream>>>(eh, h1_att, 128, ae, EE);
    edge_softmax<4><<<EE, 256, 0, stream>>>(elist, eoff, node_idx, ax, ae, alpha);
    edge_aggregate<4><<<EE, 512, 0, stream>>>(elist, eoff, node_idx, alpha, xh, oute);
    node_aggregate<4><<<NN, 512, 0, stream>>>(nlist, noff, edge_idx, alpha, oute, h1_bias, h);

    // BN2
    hipMemsetAsync(accum, 0, 256 * 4, stream);
    bn_stats<<<512, 256, 0, stream>>>(h, (long long)NN * 128 / 4, accum);
    bn_apply_f<<<1024, 256, 0, stream>>>(h, (long long)NN * 128 / 4, accum, bn2_g, bn2_b, 1.0f / NN);

    // ---- hconv2 (heads=1) ----
    edge_feat<<<EE, 128, 0, stream>>>(elist, eoff, node_idx, h, he);
    gemm_mfma<false, false, false, false, false><<<dim3(1, MB), 256, 0, stream>>>(
        h, h2T, nullptr, nullptr, xh, nullptr, NN, 128, 128);
    gemm_mfma<false, false, false, false, false><<<dim3(1, 8), 256, 0, stream>>>(
        he, h2T, nullptr, nullptr, eh, nullptr, EE, 128, 128);
    att_dots<1><<<(NN + 3) / 4, 256, 0, stream>>>(xh, h2_att, 0, ax, NN);
    att_dots<1><<<(EE + 3) / 4, 256, 0, stream>>>(eh, h2_att, 128, ae, EE);
    edge_softmax<1><<<EE, 256, 0, stream>>>(elist, eoff, node_idx, ax, ae, alpha);
    edge_aggregate<1><<<EE, 128, 0, stream>>>(elist, eoff, node_idx, alpha, xh, oute);
    node_aggregate<1><<<NN, 128, 0, stream>>>(nlist, noff, edge_idx, alpha, oute, h2_bias, h);

    // BN3
    hipMemsetAsync(accum, 0, 256 * 4, stream);
    bn_stats<<<512, 256, 0, stream>>>(h, (long long)NN * 128 / 4, accum);
    bn_apply_f<<<1024, 256, 0, stream>>>(h, (long long)NN * 128 / 4, accum, bn3_g, bn3_b, 1.0f / NN);

    // out_pre = src + leaky(h @ W2 + b2) -> bf16 scratch [MFMA + BN4 stats fused]
    hipMemsetAsync(accum, 0, 256 * 4, stream);
    gemm_mfma<true, true, true, true, true><<<dim3(8, MB), 256, 0, stream>>>(
        h, W2T, b2, x, outb, accum, NN, 128, DIN);

    // BN4: bf16 -> f32 out
    bn_apply_b2f<<<2048, 256, 0, stream>>>(outb, out, (long long)NN * DIN / 4, accum,
                                           bn4_g, bn4_b, 1.0f / (NN * PP));
}